// Round 8
// baseline (774.628 us; speedup 1.0000x reference)
//
#include <hip/hip_runtime.h>
#include <hip/hip_bf16.h>

#define DIV_UP(a,b) (((a)+(b)-1)/(b))

typedef __attribute__((ext_vector_type(8))) short short8;
typedef __attribute__((ext_vector_type(4))) float f32x4;

__device__ __forceinline__ ushort bf16_bits(float x) {
    return __builtin_bit_cast(ushort, __float2bfloat16(x));
}

// ---------------------------------------------------------------------------
// Zero ONLY the pad halos (top row + left col) of act1/act2 and vbuf.
// ---------------------------------------------------------------------------
__global__ __launch_bounds__(256) void halo_zero_kernel(
    uint4* __restrict__ act1, uint4* __restrict__ act2,
    float4* __restrict__ vbuf) {
    const int b = blockIdx.x, tid = threadIdx.x;
    const uint4 z = {0u, 0u, 0u, 0u};
    uint4* a1 = act1 + (size_t)b * 33800;          // 65*65*64 bf16 = 33800 uint4
    for (int i = tid; i < 520; i += 256) a1[i] = z;                 // row 0
    for (int i = tid; i < 512; i += 256) {                          // col 0
        int r = (i >> 3) + 1;
        a1[r * 520 + (i & 7)] = z;
    }
    uint4* a2 = act2 + (size_t)b * 17424;          // 33*33*128 bf16 = 17424 uint4
    for (int i = tid; i < 528; i += 256) a2[i] = z;                 // row 0
    for (int i = tid; i < 512; i += 256) {                          // col 0
        int r = (i >> 4) + 1;
        a2[r * 528 + (i & 15)] = z;
    }
    int idx = b * 256 + tid;
    float4 zf = {0.f, 0.f, 0.f, 0.f};
    if (idx < 16384) vbuf[idx] = zf;
}

// ---------------------------------------------------------------------------
// conv1 weights OIHW [64,3,3,3] -> fp32 [27][64]
// ---------------------------------------------------------------------------
__global__ void transpose_w1_kernel(const float* __restrict__ src,
                                    float* __restrict__ dst) {
    int t = blockIdx.x * blockDim.x + threadIdx.x;
    if (t >= 1728) return;
    int oc = t % 64;
    int r  = t / 64;
    int q  = r % 9;
    int c  = r / 9;
    dst[t] = src[(oc * 3 + c) * 9 + q];
}

// ---------------------------------------------------------------------------
// conv2/3 weights OIHW [O][C][9] fp32 -> bf16 [O][9*C], k = tap*C + c
// ---------------------------------------------------------------------------
__global__ void repack_w_kernel(const float* __restrict__ src,
                                __hip_bfloat16* __restrict__ dst, int O, int C) {
    int t = blockIdx.x * blockDim.x + threadIdx.x;
    if (t >= O * C * 9) return;
    int o   = t / (C * 9);
    int r   = t % (C * 9);
    int tap = r / C;
    int c   = r % C;
    dst[t] = __float2bfloat16(src[(o * C + c) * 9 + tap]);
}

// ---------------------------------------------------------------------------
// conv1: fp32 NCHW [CHI,3,128,128] -> bf16 padded NHWC [CHI,65,65,64], ReLU
// ---------------------------------------------------------------------------
__global__ __launch_bounds__(256) void conv1_kernel(
    const float* __restrict__ in, const float* __restrict__ wt /*[27][64]*/,
    const float* __restrict__ bias, __hip_bfloat16* __restrict__ out) {
    const int tid  = threadIdx.x;
    const int lane = tid & 63;          // ow
    const int wv   = tid >> 6;          // oc group 0..3
    const int oh   = blockIdx.x;        // 0..63
    const int b    = blockIdx.y;

    __shared__ float  sx[3][3][132];
    __shared__ ushort sc[64][72];

    const float* ip  = in + (size_t)b * 3 * 128 * 128;
    const int    ih0 = 2 * oh - 1;
    for (int e = tid; e < 1170; e += 256) {
        int c   = e / 390;
        int rem = e - c * 390;
        int r   = rem / 130;
        int col = rem - r * 130;
        int ih  = ih0 + r;
        int iw  = col - 1;
        bool ok = ((unsigned)ih < 128u) && ((unsigned)iw < 128u);
        sx[c][r][col] = ok ? ip[c * 16384 + ih * 128 + iw] : 0.f;
    }
    __syncthreads();

    const int oc0 = __builtin_amdgcn_readfirstlane(wv << 4);
    const float* wts = wt + oc0;
    float acc[16];
#pragma unroll
    for (int i = 0; i < 16; ++i) acc[i] = bias[oc0 + i];
#pragma unroll
    for (int c = 0; c < 3; ++c)
#pragma unroll
        for (int kh = 0; kh < 3; ++kh)
#pragma unroll
            for (int kw = 0; kw < 3; ++kw) {
                float x = sx[c][kh][2 * lane + kw];
                const float* wrow = wts + (c * 9 + kh * 3 + kw) * 64;
#pragma unroll
                for (int i = 0; i < 16; ++i) acc[i] = fmaf(x, wrow[i], acc[i]);
            }

#pragma unroll
    for (int h = 0; h < 2; ++h) {
        union { uint4 u4; ushort s[8]; } pk;
#pragma unroll
        for (int e = 0; e < 8; ++e)
            pk.s[e] = bf16_bits(fmaxf(acc[h * 8 + e], 0.f));
        *(uint4*)&sc[lane][oc0 + h * 8] = pk.u4;
    }
    __syncthreads();

    __hip_bfloat16* obase = out + (((size_t)b * 65 + oh + 1) * 65 + 1) * 64;
#pragma unroll
    for (int s = 0; s < 2; ++s) {
        int g   = tid * 32 + s * 16;
        int pix = g >> 7;
        int col = (g & 127) >> 1;
        uint4 val = *(const uint4*)&sc[pix][col];
        *(uint4*)((char*)obase + g) = val;
    }
}

// ---------------------------------------------------------------------------
// conv2 implicit-GEMM with register double-buffer prefetch:
// loads for K-step t+1 issued (plain global->VGPR) right after the barrier,
// consumed by ds_write at the TOP of step t+1 -> latency overlaps MFMA of t.
// ---------------------------------------------------------------------------
__global__ __launch_bounds__(256, 2) void conv2_gemm_kernel(
    const __hip_bfloat16* __restrict__ act,
    const __hip_bfloat16* __restrict__ wtB,   // [128][576]
    const float* __restrict__ bias,
    __hip_bfloat16* __restrict__ out) {
    constexpr int CIN = 64, KTOT = 576, KSTEPS = 9;
    constexpr int IPW = 65, IPH = 65;
    const int tid  = threadIdx.x;
    const int lane = tid & 63;
    const int w    = tid >> 6;
    const int l15  = lane & 15;
    const int quad = lane >> 4;
    const int Mt   = blockIdx.x;

    __shared__ __align__(16) char smem[33792];
    uint4*  As4 = (uint4*)smem;
    uint4*  Bs4 = As4 + 1024;
    ushort* Cs  = (ushort*)smem;

    const __hip_bfloat16* aBase[4];
    const __hip_bfloat16* bBase[4];
#pragma unroll
    for (int i = 0; i < 4; ++i) {
        int gi = w * 4 + i;
        int s  = gi >> 1;
        int r  = ((gi & 1) << 6) + lane;
        int m  = (Mt << 7) + r;
        int b  = m >> 10;
        int rr = m & 1023;
        int oh = rr >> 5;
        int ow = rr & 31;
        aBase[i] = act + ((size_t)(b * IPH + oh * 2) * IPW + ow * 2) * CIN + s * 8;
        bBase[i] = wtB + (size_t)r * KTOT + s * 8;
    }

    f32x4 acc[4][4];
#pragma unroll
    for (int i = 0; i < 4; ++i)
#pragma unroll
        for (int j = 0; j < 4; ++j) acc[i][j] = (f32x4){0.f, 0.f, 0.f, 0.f};

    const int wm = (w & 1) << 6;
    const int wn = (w >> 1) << 6;

    // prologue: prefetch K-step 0 into registers
    uint4 ar[4], br[4];
#pragma unroll
    for (int i = 0; i < 4; ++i) {
        ar[i] = *(const uint4*)(aBase[i]);
        br[i] = *(const uint4*)(bBase[i]);
    }

    for (int t = 0; t < KSTEPS; ++t) {
        // write staged regs to LDS (s_waitcnt for loads lands here)
#pragma unroll
        for (int i = 0; i < 4; ++i) {
            int gi = w * 4 + i;
            As4[gi * 64 + lane] = ar[i];
            Bs4[gi * 64 + lane] = br[i];
        }
        __syncthreads();
        // issue prefetch for t+1 (overlaps the MFMA stream below)
        if (t + 1 < KSTEPS) {
            int kh = (t + 1) / 3, kw = (t + 1) - kh * 3;
            int aoff = (kh * IPW + kw) * CIN;
#pragma unroll
            for (int i = 0; i < 4; ++i) {
                ar[i] = *(const uint4*)(aBase[i] + aoff);
                br[i] = *(const uint4*)(bBase[i] + (t + 1) * 64);
            }
        }
#pragma unroll
        for (int ks = 0; ks < 2; ++ks) {
            short8 af[4], bf[4];
#pragma unroll
            for (int i = 0; i < 4; ++i) {
                int sF = ks * 4 + quad;
                af[i] = __builtin_bit_cast(short8, As4[sF * 128 + wm + i * 16 + l15]);
                bf[i] = __builtin_bit_cast(short8, Bs4[sF * 128 + wn + i * 16 + l15]);
            }
#pragma unroll
            for (int i = 0; i < 4; ++i)
#pragma unroll
                for (int j = 0; j < 4; ++j)
                    acc[i][j] = __builtin_amdgcn_mfma_f32_16x16x32_bf16(
                        af[i], bf[j], acc[i][j], 0, 0, 0);
        }
        __syncthreads();   // all frag reads done before next overwrite
    }

    // epilogue: bias+ReLU -> bf16 tile in LDS -> coalesced 8B stores
#pragma unroll
    for (int j = 0; j < 4; ++j) {
        int n = wn + j * 16 + l15;
        float bv = bias[n];
#pragma unroll
        for (int i = 0; i < 4; ++i)
#pragma unroll
            for (int r = 0; r < 4; ++r) {
                int ml = wm + i * 16 + quad * 4 + r;
                Cs[ml * 132 + n] = bf16_bits(fmaxf(acc[i][j][r] + bv, 0.f));
            }
    }
    __syncthreads();
#pragma unroll
    for (int q = 0; q < 16; ++q) {
        int c   = tid + 256 * q;
        int row = c >> 5;
        int off = c & 31;
        uint2 val = *(const uint2*)(Cs + row * 132 + off * 4);
        int m  = (Mt << 7) + row;
        int b  = m >> 10;
        int rr = m & 1023;
        int oh = rr >> 5;
        int ow = rr & 31;
        size_t pix = ((size_t)(b * 33 + oh + 1) * 33 + (ow + 1));
        *(uint2*)(out + pix * 128 + off * 4) = val;
    }
}

// ---------------------------------------------------------------------------
// conv3 implicit-GEMM + fused global-avg-pool, same reg-prefetch pipeline
// ---------------------------------------------------------------------------
__global__ __launch_bounds__(256, 2) void conv3_gemm_pool_kernel(
    const __hip_bfloat16* __restrict__ act,
    const __hip_bfloat16* __restrict__ wtB,   // [256][1152]
    const float* __restrict__ bias,
    float* __restrict__ v /* [CHI,256], pre-zeroed */) {
    constexpr int CIN = 128, KTOT = 1152, KSTEPS = 18;
    constexpr int IPW = 33, IPH = 33;
    const int tid  = threadIdx.x;
    const int lane = tid & 63;
    const int w    = tid >> 6;
    const int l15  = lane & 15;
    const int quad = lane >> 4;
    const int Mt   = blockIdx.x;
    const int N0   = blockIdx.y * 128;

    __shared__ uint4 As4[1024];
    __shared__ uint4 Bs4[1024];
    __shared__ float sred[128][2];

    const __hip_bfloat16* aBase[4];
    const __hip_bfloat16* bBase[4];
#pragma unroll
    for (int i = 0; i < 4; ++i) {
        int gi = w * 4 + i;
        int s  = gi >> 1;
        int r  = ((gi & 1) << 6) + lane;
        int m  = (Mt << 7) + r;
        int b  = m >> 8;
        int rr = m & 255;
        int oh = rr >> 4;
        int ow = rr & 15;
        aBase[i] = act + ((size_t)(b * IPH + oh * 2) * IPW + ow * 2) * CIN + s * 8;
        bBase[i] = wtB + (size_t)(N0 + r) * KTOT + s * 8;
    }

    f32x4 acc[4][4];
#pragma unroll
    for (int i = 0; i < 4; ++i)
#pragma unroll
        for (int j = 0; j < 4; ++j) acc[i][j] = (f32x4){0.f, 0.f, 0.f, 0.f};

    const int wm = (w & 1) << 6;
    const int wn = (w >> 1) << 6;

    uint4 ar[4], br[4];
#pragma unroll
    for (int i = 0; i < 4; ++i) {
        ar[i] = *(const uint4*)(aBase[i]);
        br[i] = *(const uint4*)(bBase[i]);
    }

    for (int t = 0; t < KSTEPS; ++t) {
#pragma unroll
        for (int i = 0; i < 4; ++i) {
            int gi = w * 4 + i;
            As4[gi * 64 + lane] = ar[i];
            Bs4[gi * 64 + lane] = br[i];
        }
        __syncthreads();
        if (t + 1 < KSTEPS) {
            int tn  = t + 1;
            int tap = tn >> 1, c0 = (tn & 1) << 6;
            int kh = tap / 3, kw = tap - kh * 3;
            int aoff = (kh * IPW + kw) * CIN + c0;
#pragma unroll
            for (int i = 0; i < 4; ++i) {
                ar[i] = *(const uint4*)(aBase[i] + aoff);
                br[i] = *(const uint4*)(bBase[i] + tn * 64);
            }
        }
#pragma unroll
        for (int ks = 0; ks < 2; ++ks) {
            short8 af[4], bf[4];
#pragma unroll
            for (int i = 0; i < 4; ++i) {
                int sF = ks * 4 + quad;
                af[i] = __builtin_bit_cast(short8, As4[sF * 128 + wm + i * 16 + l15]);
                bf[i] = __builtin_bit_cast(short8, Bs4[sF * 128 + wn + i * 16 + l15]);
            }
#pragma unroll
            for (int i = 0; i < 4; ++i)
#pragma unroll
                for (int j = 0; j < 4; ++j)
                    acc[i][j] = __builtin_amdgcn_mfma_f32_16x16x32_bf16(
                        af[i], bf[j], acc[i][j], 0, 0, 0);
        }
        __syncthreads();
    }

    float s4[4];
#pragma unroll
    for (int j = 0; j < 4; ++j) {
        float bv = bias[N0 + wn + j * 16 + l15];
        float s = 0.f;
#pragma unroll
        for (int i = 0; i < 4; ++i)
#pragma unroll
            for (int r = 0; r < 4; ++r)
                s += fmaxf(acc[i][j][r] + bv, 0.f);
        s += __shfl_xor(s, 16, 64);
        s += __shfl_xor(s, 32, 64);
        s4[j] = s;
    }
    if (quad == 0) {
#pragma unroll
        for (int j = 0; j < 4; ++j) sred[wn + j * 16 + l15][w & 1] = s4[j];
    }
    __syncthreads();
    if (tid < 128) {
        float val = (sred[tid][0] + sred[tid][1]) * (1.f / 256.f);
        int bimg = Mt >> 1;
        atomicAdd(v + (size_t)bimg * 256 + N0 + tid, val);
    }
}

// ---------------------------------------------------------------------------
// Tail: one block (256 thr) per sample; K-split GEMV stages, float4 weights.
// ---------------------------------------------------------------------------
template<int N, int K, int S, bool RELU>
__device__ __forceinline__ void gemv_stage(const float* __restrict__ w,
                                           const float* __restrict__ bias,
                                           const float* in, float* outv,
                                           float4* red4, int tid) {
    constexpr int G = N / 4;
    constexpr int CHK = K / S;
    static_assert(G * S == 256 && CHK * S == K, "stage shape");
    const int g = tid % G, s = tid / G;
    const float4* wp = (const float4*)w;
    float4 a; a.x = a.y = a.z = a.w = 0.f;
    const int k0 = s * CHK;
#pragma unroll 8
    for (int i = 0; i < CHK; ++i) {
        float x = in[k0 + i];
        float4 wv = wp[(size_t)(k0 + i) * G + g];
        a.x = fmaf(x, wv.x, a.x);
        a.y = fmaf(x, wv.y, a.y);
        a.z = fmaf(x, wv.z, a.z);
        a.w = fmaf(x, wv.w, a.w);
    }
    red4[tid] = a;
    __syncthreads();
    if (tid < N) {
        int gg = tid >> 2, e = tid & 3;
        float vv = bias[tid];
#pragma unroll
        for (int ss = 0; ss < S; ++ss) {
            const float* rp = (const float*)(red4 + ss * G + gg);
            vv += rp[e];
        }
        if (RELU) vv = fmaxf(vv, 0.f);
        outv[tid] = vv;
    }
    __syncthreads();
}

__global__ __launch_bounds__(256) void tail_kernel(
    const float* __restrict__ prop, const int* __restrict__ task_ids,
    const float* __restrict__ p1_w, const float* __restrict__ p1_b,
    const float* __restrict__ p2_w, const float* __restrict__ p2_b,
    const float* __restrict__ v,
    const float* __restrict__ f1_w, const float* __restrict__ f1_b,
    const float* __restrict__ f2_w, const float* __restrict__ f2_b,
    const float* __restrict__ task_emb,
    const float* __restrict__ g_w, const float* __restrict__ g_b,
    const float* __restrict__ h1_w, const float* __restrict__ h1_b,
    const float* __restrict__ h2_w, const float* __restrict__ h2_b,
    const float* __restrict__ h3_w, const float* __restrict__ h3_b,
    float* __restrict__ out) {
    const int b   = blockIdx.x;
    const int tid = threadIdx.x;
    const int t   = task_ids[b];
    __shared__ float sa[320];
    __shared__ float sb[288];
    __shared__ float sph[64];
    __shared__ float4 red4[256];

    sa[tid] = (tid < 256) ? v[(size_t)b * 256 + tid] : 0.f;
    if (tid < 64) {
        float h = p1_b[tid];
#pragma unroll
        for (int k = 0; k < 7; ++k) h = fmaf(prop[b * 7 + k], p1_w[k * 64 + tid], h);
        sph[tid] = fmaxf(h, 0.f);
    }
    __syncthreads();
    gemv_stage<64, 64, 16, false>(p2_w, p2_b, sph, sa + 256, red4, tid);
    gemv_stage<256, 320, 4, true>(f1_w, f1_b, sa, sb, red4, tid);
    gemv_stage<256, 256, 4, true>(f2_w, f2_b, sb, sa, red4, tid);
    if (tid < 32) sa[256 + tid] = task_emb[t * 32 + tid];
    __syncthreads();
    gemv_stage<256, 288, 4, true>(g_w, g_b, sa, sb, red4, tid);
    gemv_stage<128, 256, 8, true>(h1_w + (size_t)t * 32768, h1_b + t * 128,
                                  sb, sa, red4, tid);
    gemv_stage<128, 128, 8, true>(h2_w + (size_t)t * 16384, h2_b + t * 128,
                                  sa, sb, red4, tid);
    if (tid < 128) {
        float4 wv = ((const float4*)(h3_w + (size_t)t * 512))[tid];
        float x = sb[tid];
        float r0 = x * wv.x, r1 = x * wv.y, r2 = x * wv.z, r3 = x * wv.w;
#pragma unroll
        for (int off = 1; off < 64; off <<= 1) {
            r0 += __shfl_xor(r0, off, 64);
            r1 += __shfl_xor(r1, off, 64);
            r2 += __shfl_xor(r2, off, 64);
            r3 += __shfl_xor(r3, off, 64);
        }
        if ((tid & 63) == 0) {
            float4 rv; rv.x = r0; rv.y = r1; rv.z = r2; rv.w = r3;
            red4[tid >> 6] = rv;
        }
    }
    __syncthreads();
    if (tid < 4) {
        const float* ra = (const float*)(red4 + 0);
        const float* rb = (const float*)(red4 + 1);
        out[b * 4 + tid] = ra[tid] + rb[tid] + h3_b[t * 4 + tid];
    }
}

// ---------------------------------------------------------------------------
extern "C" void kernel_launch(void* const* d_in, const int* in_sizes, int n_in,
                              void* d_out, int out_size, void* d_ws, size_t ws_size,
                              hipStream_t stream) {
    (void)in_sizes; (void)n_in; (void)out_size;
    const float* images   = (const float*)d_in[0];
    const float* prop     = (const float*)d_in[1];
    const int*   task_ids = (const int*)d_in[2];
    const float* c1_w = (const float*)d_in[3];
    const float* c1_b = (const float*)d_in[4];
    const float* c2_w = (const float*)d_in[5];
    const float* c2_b = (const float*)d_in[6];
    const float* c3_w = (const float*)d_in[7];
    const float* c3_b = (const float*)d_in[8];
    const float* p1_w = (const float*)d_in[9];
    const float* p1_b = (const float*)d_in[10];
    const float* p2_w = (const float*)d_in[11];
    const float* p2_b = (const float*)d_in[12];
    const float* f1_w = (const float*)d_in[13];
    const float* f1_b = (const float*)d_in[14];
    const float* f2_w = (const float*)d_in[15];
    const float* f2_b = (const float*)d_in[16];
    const float* temb = (const float*)d_in[17];
    const float* g_w  = (const float*)d_in[18];
    const float* g_b  = (const float*)d_in[19];
    const float* h1_w = (const float*)d_in[20];
    const float* h1_b = (const float*)d_in[21];
    const float* h2_w = (const float*)d_in[22];
    const float* h2_b = (const float*)d_in[23];
    const float* h3_w = (const float*)d_in[24];
    const float* h3_b = (const float*)d_in[25];
    float* out = (float*)d_out;

    const size_t per_img = (size_t)65 * 65 * 64 * 2 + (size_t)33 * 33 * 128 * 2;
    const size_t fixed   = (size_t)256 * 256 * 4 + 1728 * 4 +
                           (size_t)73728 * 2 + (size_t)294912 * 2 + 4096;
    int CHI = 64;
    if (ws_size >= fixed + per_img * 256) CHI = 256;
    else if (ws_size >= fixed + per_img * 128) CHI = 128;

    char* ws = (char*)d_ws;
    size_t off = 0;
    auto alloc = [&](size_t bytes) {
        void* p = ws + off;
        off += (bytes + 255) & ~(size_t)255;
        return p;
    };
    __hip_bfloat16* act1 = (__hip_bfloat16*)alloc((size_t)CHI * 65 * 65 * 64 * 2);
    __hip_bfloat16* act2 = (__hip_bfloat16*)alloc((size_t)CHI * 33 * 33 * 128 * 2);
    float*          vbuf = (float*)alloc((size_t)256 * 256 * 4);
    float*          w1t  = (float*)alloc((size_t)1728 * 4);
    __hip_bfloat16* w2t  = (__hip_bfloat16*)alloc((size_t)73728 * 2);
    __hip_bfloat16* w3t  = (__hip_bfloat16*)alloc((size_t)294912 * 2);

    halo_zero_kernel<<<dim3(CHI), 256, 0, stream>>>(
        (uint4*)act1, (uint4*)act2, (float4*)vbuf);
    transpose_w1_kernel<<<DIV_UP(1728, 256), 256, 0, stream>>>(c1_w, w1t);
    repack_w_kernel<<<DIV_UP(73728, 256), 256, 0, stream>>>(c2_w, w2t, 128, 64);
    repack_w_kernel<<<DIV_UP(294912, 256), 256, 0, stream>>>(c3_w, w3t, 256, 128);

    for (int c0 = 0; c0 < 256; c0 += CHI) {
        const float* img_c = images + (size_t)c0 * 3 * 128 * 128;
        conv1_kernel<<<dim3(64, CHI), dim3(256), 0, stream>>>(
            img_c, w1t, c1_b, act1);
        conv2_gemm_kernel<<<dim3(CHI * 8), 256, 0, stream>>>(
            act1, w2t, c2_b, act2);
        conv3_gemm_pool_kernel<<<dim3(CHI * 2, 2), 256, 0, stream>>>(
            act2, w3t, c3_b, vbuf + (size_t)c0 * 256);
    }
    tail_kernel<<<256, 256, 0, stream>>>(prop, task_ids, p1_w, p1_b, p2_w, p2_b,
                                         vbuf, f1_w, f1_b, f2_w, f2_b, temb,
                                         g_w, g_b, h1_w, h1_b, h2_w, h2_b,
                                         h3_w, h3_b, out);
}

// Round 9
// 413.257 us; speedup vs baseline: 1.8744x; 1.8744x over previous
//
#include <hip/hip_runtime.h>
#include <hip/hip_bf16.h>

#define DIV_UP(a,b) (((a)+(b)-1)/(b))

typedef __attribute__((ext_vector_type(8))) short short8;
typedef __attribute__((ext_vector_type(4))) float f32x4;

__device__ __forceinline__ void gld_lds16(const void* g, void* l) {
    __builtin_amdgcn_global_load_lds(
        (const __attribute__((address_space(1))) void*)g,
        (__attribute__((address_space(3))) void*)l, 16, 0, 0);
}

__device__ __forceinline__ ushort bf16_bits(float x) {
    return __builtin_bit_cast(ushort, __float2bfloat16(x));
}

// ---------------------------------------------------------------------------
// Zero ONLY the pad halos (top row + left col) of act1/act2 and vbuf.
// ---------------------------------------------------------------------------
__global__ __launch_bounds__(256) void halo_zero_kernel(
    uint4* __restrict__ act1, uint4* __restrict__ act2,
    float4* __restrict__ vbuf) {
    const int b = blockIdx.x, tid = threadIdx.x;
    const uint4 z = {0u, 0u, 0u, 0u};
    uint4* a1 = act1 + (size_t)b * 33800;          // 65*65*64 bf16 = 33800 uint4
    for (int i = tid; i < 520; i += 256) a1[i] = z;
    for (int i = tid; i < 512; i += 256) {
        int r = (i >> 3) + 1;
        a1[r * 520 + (i & 7)] = z;
    }
    uint4* a2 = act2 + (size_t)b * 17424;          // 33*33*128 bf16 = 17424 uint4
    for (int i = tid; i < 528; i += 256) a2[i] = z;
    for (int i = tid; i < 512; i += 256) {
        int r = (i >> 4) + 1;
        a2[r * 528 + (i & 15)] = z;
    }
    int idx = b * 256 + tid;
    float4 zf = {0.f, 0.f, 0.f, 0.f};
    if (idx < 16384) vbuf[idx] = zf;
}

// ---------------------------------------------------------------------------
// conv1 weights OIHW [64,3,3,3] -> fp32 [27][64]
// ---------------------------------------------------------------------------
__global__ void transpose_w1_kernel(const float* __restrict__ src,
                                    float* __restrict__ dst) {
    int t = blockIdx.x * blockDim.x + threadIdx.x;
    if (t >= 1728) return;
    int oc = t % 64;
    int r  = t / 64;
    int q  = r % 9;
    int c  = r / 9;
    dst[t] = src[(oc * 3 + c) * 9 + q];
}

// ---------------------------------------------------------------------------
// conv2/3 weights OIHW [O][C][9] fp32 -> bf16 [O][9*C], k = tap*C + c
// ---------------------------------------------------------------------------
__global__ void repack_w_kernel(const float* __restrict__ src,
                                __hip_bfloat16* __restrict__ dst, int O, int C) {
    int t = blockIdx.x * blockDim.x + threadIdx.x;
    if (t >= O * C * 9) return;
    int o   = t / (C * 9);
    int r   = t % (C * 9);
    int tap = r / C;
    int c   = r % C;
    dst[t] = __float2bfloat16(src[(o * C + c) * 9 + tap]);
}

// ---------------------------------------------------------------------------
// conv1: fp32 NCHW [CHI,3,128,128] -> bf16 padded NHWC [CHI,65,65,64], ReLU
// ---------------------------------------------------------------------------
__global__ __launch_bounds__(256) void conv1_kernel(
    const float* __restrict__ in, const float* __restrict__ wt /*[27][64]*/,
    const float* __restrict__ bias, __hip_bfloat16* __restrict__ out) {
    const int tid  = threadIdx.x;
    const int lane = tid & 63;          // ow
    const int wv   = tid >> 6;          // oc group 0..3
    const int oh   = blockIdx.x;        // 0..63
    const int b    = blockIdx.y;

    __shared__ float  sx[3][3][132];
    __shared__ ushort sc[64][72];

    const float* ip  = in + (size_t)b * 3 * 128 * 128;
    const int    ih0 = 2 * oh - 1;
    for (int e = tid; e < 1170; e += 256) {
        int c   = e / 390;
        int rem = e - c * 390;
        int r   = rem / 130;
        int col = rem - r * 130;
        int ih  = ih0 + r;
        int iw  = col - 1;
        bool ok = ((unsigned)ih < 128u) && ((unsigned)iw < 128u);
        sx[c][r][col] = ok ? ip[c * 16384 + ih * 128 + iw] : 0.f;
    }
    __syncthreads();

    const int oc0 = __builtin_amdgcn_readfirstlane(wv << 4);
    const float* wts = wt + oc0;
    float acc[16];
#pragma unroll
    for (int i = 0; i < 16; ++i) acc[i] = bias[oc0 + i];
#pragma unroll
    for (int c = 0; c < 3; ++c)
#pragma unroll
        for (int kh = 0; kh < 3; ++kh)
#pragma unroll
            for (int kw = 0; kw < 3; ++kw) {
                float x = sx[c][kh][2 * lane + kw];
                const float* wrow = wts + (c * 9 + kh * 3 + kw) * 64;
#pragma unroll
                for (int i = 0; i < 16; ++i) acc[i] = fmaf(x, wrow[i], acc[i]);
            }

#pragma unroll
    for (int h = 0; h < 2; ++h) {
        union { uint4 u4; ushort s[8]; } pk;
#pragma unroll
        for (int e = 0; e < 8; ++e)
            pk.s[e] = bf16_bits(fmaxf(acc[h * 8 + e], 0.f));
        *(uint4*)&sc[lane][oc0 + h * 8] = pk.u4;
    }
    __syncthreads();

    __hip_bfloat16* obase = out + (((size_t)b * 65 + oh + 1) * 65 + 1) * 64;
#pragma unroll
    for (int s = 0; s < 2; ++s) {
        int g   = tid * 32 + s * 16;
        int pix = g >> 7;
        int col = (g & 127) >> 1;
        uint4 val = *(const uint4*)&sc[pix][col];
        *(uint4*)((char*)obase + g) = val;
    }
}

// ---------------------------------------------------------------------------
// conv2 implicit-GEMM, ping-pong LDS double-buffer (one barrier per K-step;
// global_load_lds for t+1 issued into the other buffer right after the
// barrier, so its vmcnt drain overlaps step t's MFMA). XCD swizzle on Mt.
// ---------------------------------------------------------------------------
__global__ __launch_bounds__(256, 2) void conv2_gemm_kernel(
    const __hip_bfloat16* __restrict__ act,
    const __hip_bfloat16* __restrict__ wtB,   // [128][576]
    const float* __restrict__ bias,
    __hip_bfloat16* __restrict__ out) {
    constexpr int CIN = 64, KTOT = 576, KSTEPS = 9;
    constexpr int IPW = 65, IPH = 65;
    const int tid  = threadIdx.x;
    const int lane = tid & 63;
    const int w    = tid >> 6;
    const int l15  = lane & 15;
    const int quad = lane >> 4;
    // XCD-aware swizzle: same-image M-tiles land on the same XCD, close in time
    const int per = gridDim.x >> 3;
    const int Mt  = (blockIdx.x & 7) * per + (blockIdx.x >> 3);

    __shared__ __align__(16) char smem[65536];
    uint4*  As4 = (uint4*)smem;              // [2][1024] uint4 (16 KB each)
    uint4*  Bs4 = (uint4*)(smem + 32768);    // [2][1024]
    ushort* Cs  = (ushort*)smem;             // epilogue alias

    const __hip_bfloat16* aBase[4];
    const __hip_bfloat16* bBase[4];
#pragma unroll
    for (int i = 0; i < 4; ++i) {
        int gi = w * 4 + i;
        int s  = gi >> 1;
        int r  = ((gi & 1) << 6) + lane;
        int m  = (Mt << 7) + r;
        int b  = m >> 10;
        int rr = m & 1023;
        int oh = rr >> 5;
        int ow = rr & 31;
        aBase[i] = act + ((size_t)(b * IPH + oh * 2) * IPW + ow * 2) * CIN + s * 8;
        bBase[i] = wtB + (size_t)r * KTOT + s * 8;
    }

    f32x4 acc[4][4];
#pragma unroll
    for (int i = 0; i < 4; ++i)
#pragma unroll
        for (int j = 0; j < 4; ++j) acc[i][j] = (f32x4){0.f, 0.f, 0.f, 0.f};

    const int wm = (w & 1) << 6;
    const int wn = (w >> 1) << 6;

    // prologue: stage K-step 0 into buffer 0 (tap 0 -> aoff = 0)
#pragma unroll
    for (int i = 0; i < 4; ++i) {
        int gi = w * 4 + i;
        gld_lds16(aBase[i], As4 + gi * 64);
        gld_lds16(bBase[i], Bs4 + gi * 64);
    }

    for (int t = 0; t < KSTEPS; ++t) {
        __syncthreads();   // drains step-t loads (issued a full step ago, t>0)
        if (t + 1 < KSTEPS) {
            int tn = t + 1;
            int kh = tn / 3, kw = tn - kh * 3;
            int aoff = (kh * IPW + kw) * CIN;
            int buf  = (tn & 1) << 10;
#pragma unroll
            for (int i = 0; i < 4; ++i) {
                int gi = w * 4 + i;
                gld_lds16(aBase[i] + aoff, As4 + buf + gi * 64);
                gld_lds16(bBase[i] + tn * 64, Bs4 + buf + gi * 64);
            }
        }
        const uint4* Ab = As4 + ((t & 1) << 10);
        const uint4* Bb = Bs4 + ((t & 1) << 10);
#pragma unroll
        for (int ks = 0; ks < 2; ++ks) {
            short8 af[4], bf[4];
#pragma unroll
            for (int i = 0; i < 4; ++i) {
                int sF = ks * 4 + quad;
                af[i] = __builtin_bit_cast(short8, Ab[sF * 128 + wm + i * 16 + l15]);
                bf[i] = __builtin_bit_cast(short8, Bb[sF * 128 + wn + i * 16 + l15]);
            }
#pragma unroll
            for (int i = 0; i < 4; ++i)
#pragma unroll
                for (int j = 0; j < 4; ++j)
                    acc[i][j] = __builtin_amdgcn_mfma_f32_16x16x32_bf16(
                        af[i], bf[j], acc[i][j], 0, 0, 0);
        }
    }

    // epilogue: bias+ReLU -> bf16 tile in LDS -> coalesced 8B stores
    __syncthreads();
#pragma unroll
    for (int j = 0; j < 4; ++j) {
        int n = wn + j * 16 + l15;
        float bv = bias[n];
#pragma unroll
        for (int i = 0; i < 4; ++i)
#pragma unroll
            for (int r = 0; r < 4; ++r) {
                int ml = wm + i * 16 + quad * 4 + r;
                Cs[ml * 132 + n] = bf16_bits(fmaxf(acc[i][j][r] + bv, 0.f));
            }
    }
    __syncthreads();
#pragma unroll
    for (int q = 0; q < 16; ++q) {
        int c   = tid + 256 * q;
        int row = c >> 5;
        int off = c & 31;
        uint2 val = *(const uint2*)(Cs + row * 132 + off * 4);
        int m  = (Mt << 7) + row;
        int b  = m >> 10;
        int rr = m & 1023;
        int oh = rr >> 5;
        int ow = rr & 31;
        size_t pix = ((size_t)(b * 33 + oh + 1) * 33 + (ow + 1));
        *(uint2*)(out + pix * 128 + off * 4) = val;
    }
}

// ---------------------------------------------------------------------------
// conv3 implicit-GEMM + fused global-avg-pool, ping-pong dbuf + XCD swizzle.
// sred aliases into buffer 0 (final K-step uses buffer 1 -> no overlap).
// ---------------------------------------------------------------------------
__global__ __launch_bounds__(256, 2) void conv3_gemm_pool_kernel(
    const __hip_bfloat16* __restrict__ act,
    const __hip_bfloat16* __restrict__ wtB,   // [256][1152]
    const float* __restrict__ bias,
    float* __restrict__ v /* [CHI,256], pre-zeroed */) {
    constexpr int CIN = 128, KTOT = 1152, KSTEPS = 18;  // even: last buf = 1
    constexpr int IPW = 33, IPH = 33;
    const int tid  = threadIdx.x;
    const int lane = tid & 63;
    const int w    = tid >> 6;
    const int l15  = lane & 15;
    const int quad = lane >> 4;
    const int per = gridDim.x >> 3;
    const int Mt  = (blockIdx.x & 7) * per + (blockIdx.x >> 3);
    const int N0   = blockIdx.y * 128;

    __shared__ __align__(16) char smem[65536];
    uint4* As4  = (uint4*)smem;
    uint4* Bs4  = (uint4*)(smem + 32768);
    float* sred = (float*)smem;              // 1 KB alias in buffer 0 region

    const __hip_bfloat16* aBase[4];
    const __hip_bfloat16* bBase[4];
#pragma unroll
    for (int i = 0; i < 4; ++i) {
        int gi = w * 4 + i;
        int s  = gi >> 1;
        int r  = ((gi & 1) << 6) + lane;
        int m  = (Mt << 7) + r;
        int b  = m >> 8;
        int rr = m & 255;
        int oh = rr >> 4;
        int ow = rr & 15;
        aBase[i] = act + ((size_t)(b * IPH + oh * 2) * IPW + ow * 2) * CIN + s * 8;
        bBase[i] = wtB + (size_t)(N0 + r) * KTOT + s * 8;
    }

    f32x4 acc[4][4];
#pragma unroll
    for (int i = 0; i < 4; ++i)
#pragma unroll
        for (int j = 0; j < 4; ++j) acc[i][j] = (f32x4){0.f, 0.f, 0.f, 0.f};

    const int wm = (w & 1) << 6;
    const int wn = (w >> 1) << 6;

    // prologue: stage K-step 0 into buffer 0 (tap 0, c0 = 0 -> aoff = 0)
#pragma unroll
    for (int i = 0; i < 4; ++i) {
        int gi = w * 4 + i;
        gld_lds16(aBase[i], As4 + gi * 64);
        gld_lds16(bBase[i], Bs4 + gi * 64);
    }

    for (int t = 0; t < KSTEPS; ++t) {
        __syncthreads();
        if (t + 1 < KSTEPS) {
            int tn  = t + 1;
            int tap = tn >> 1, c0 = (tn & 1) << 6;
            int kh = tap / 3, kw = tap - kh * 3;
            int aoff = (kh * IPW + kw) * CIN + c0;
            int buf  = (tn & 1) << 10;
#pragma unroll
            for (int i = 0; i < 4; ++i) {
                int gi = w * 4 + i;
                gld_lds16(aBase[i] + aoff, As4 + buf + gi * 64);
                gld_lds16(bBase[i] + tn * 64, Bs4 + buf + gi * 64);
            }
        }
        const uint4* Ab = As4 + ((t & 1) << 10);
        const uint4* Bb = Bs4 + ((t & 1) << 10);
#pragma unroll
        for (int ks = 0; ks < 2; ++ks) {
            short8 af[4], bf[4];
#pragma unroll
            for (int i = 0; i < 4; ++i) {
                int sF = ks * 4 + quad;
                af[i] = __builtin_bit_cast(short8, Ab[sF * 128 + wm + i * 16 + l15]);
                bf[i] = __builtin_bit_cast(short8, Bb[sF * 128 + wn + i * 16 + l15]);
            }
#pragma unroll
            for (int i = 0; i < 4; ++i)
#pragma unroll
                for (int j = 0; j < 4; ++j)
                    acc[i][j] = __builtin_amdgcn_mfma_f32_16x16x32_bf16(
                        af[i], bf[j], acc[i][j], 0, 0, 0);
        }
    }

    // fused pool: bias+ReLU, sum over this block's 128 spatial positions.
    // Final K-step read buffer 1 (t=17); sred (1 KB) sits in buffer 0 — safe.
    float s4[4];
#pragma unroll
    for (int j = 0; j < 4; ++j) {
        float bv = bias[N0 + wn + j * 16 + l15];
        float s = 0.f;
#pragma unroll
        for (int i = 0; i < 4; ++i)
#pragma unroll
            for (int r = 0; r < 4; ++r)
                s += fmaxf(acc[i][j][r] + bv, 0.f);
        s += __shfl_xor(s, 16, 64);
        s += __shfl_xor(s, 32, 64);
        s4[j] = s;
    }
    if (quad == 0) {
#pragma unroll
        for (int j = 0; j < 4; ++j) sred[(wn + j * 16 + l15) * 2 + (w & 1)] = s4[j];
    }
    __syncthreads();
    if (tid < 128) {
        float val = (sred[tid * 2] + sred[tid * 2 + 1]) * (1.f / 256.f);
        int bimg = Mt >> 1;
        atomicAdd(v + (size_t)bimg * 256 + N0 + tid, val);
    }
}

// ---------------------------------------------------------------------------
// Tail: one block (256 thr) per sample; K-split GEMV stages, float4 weights.
// ---------------------------------------------------------------------------
template<int N, int K, int S, bool RELU>
__device__ __forceinline__ void gemv_stage(const float* __restrict__ w,
                                           const float* __restrict__ bias,
                                           const float* in, float* outv,
                                           float4* red4, int tid) {
    constexpr int G = N / 4;
    constexpr int CHK = K / S;
    static_assert(G * S == 256 && CHK * S == K, "stage shape");
    const int g = tid % G, s = tid / G;
    const float4* wp = (const float4*)w;
    float4 a; a.x = a.y = a.z = a.w = 0.f;
    const int k0 = s * CHK;
#pragma unroll 8
    for (int i = 0; i < CHK; ++i) {
        float x = in[k0 + i];
        float4 wv = wp[(size_t)(k0 + i) * G + g];
        a.x = fmaf(x, wv.x, a.x);
        a.y = fmaf(x, wv.y, a.y);
        a.z = fmaf(x, wv.z, a.z);
        a.w = fmaf(x, wv.w, a.w);
    }
    red4[tid] = a;
    __syncthreads();
    if (tid < N) {
        int gg = tid >> 2, e = tid & 3;
        float vv = bias[tid];
#pragma unroll
        for (int ss = 0; ss < S; ++ss) {
            const float* rp = (const float*)(red4 + ss * G + gg);
            vv += rp[e];
        }
        if (RELU) vv = fmaxf(vv, 0.f);
        outv[tid] = vv;
    }
    __syncthreads();
}

__global__ __launch_bounds__(256) void tail_kernel(
    const float* __restrict__ prop, const int* __restrict__ task_ids,
    const float* __restrict__ p1_w, const float* __restrict__ p1_b,
    const float* __restrict__ p2_w, const float* __restrict__ p2_b,
    const float* __restrict__ v,
    const float* __restrict__ f1_w, const float* __restrict__ f1_b,
    const float* __restrict__ f2_w, const float* __restrict__ f2_b,
    const float* __restrict__ task_emb,
    const float* __restrict__ g_w, const float* __restrict__ g_b,
    const float* __restrict__ h1_w, const float* __restrict__ h1_b,
    const float* __restrict__ h2_w, const float* __restrict__ h2_b,
    const float* __restrict__ h3_w, const float* __restrict__ h3_b,
    float* __restrict__ out) {
    const int b   = blockIdx.x;
    const int tid = threadIdx.x;
    const int t   = task_ids[b];
    __shared__ float sa[320];
    __shared__ float sb[288];
    __shared__ float sph[64];
    __shared__ float4 red4[256];

    sa[tid] = (tid < 256) ? v[(size_t)b * 256 + tid] : 0.f;
    if (tid < 64) {
        float h = p1_b[tid];
#pragma unroll
        for (int k = 0; k < 7; ++k) h = fmaf(prop[b * 7 + k], p1_w[k * 64 + tid], h);
        sph[tid] = fmaxf(h, 0.f);
    }
    __syncthreads();
    gemv_stage<64, 64, 16, false>(p2_w, p2_b, sph, sa + 256, red4, tid);
    gemv_stage<256, 320, 4, true>(f1_w, f1_b, sa, sb, red4, tid);
    gemv_stage<256, 256, 4, true>(f2_w, f2_b, sb, sa, red4, tid);
    if (tid < 32) sa[256 + tid] = task_emb[t * 32 + tid];
    __syncthreads();
    gemv_stage<256, 288, 4, true>(g_w, g_b, sa, sb, red4, tid);
    gemv_stage<128, 256, 8, true>(h1_w + (size_t)t * 32768, h1_b + t * 128,
                                  sb, sa, red4, tid);
    gemv_stage<128, 128, 8, true>(h2_w + (size_t)t * 16384, h2_b + t * 128,
                                  sa, sb, red4, tid);
    if (tid < 128) {
        float4 wv = ((const float4*)(h3_w + (size_t)t * 512))[tid];
        float x = sb[tid];
        float r0 = x * wv.x, r1 = x * wv.y, r2 = x * wv.z, r3 = x * wv.w;
#pragma unroll
        for (int off = 1; off < 64; off <<= 1) {
            r0 += __shfl_xor(r0, off, 64);
            r1 += __shfl_xor(r1, off, 64);
            r2 += __shfl_xor(r2, off, 64);
            r3 += __shfl_xor(r3, off, 64);
        }
        if ((tid & 63) == 0) {
            float4 rv; rv.x = r0; rv.y = r1; rv.z = r2; rv.w = r3;
            red4[tid >> 6] = rv;
        }
    }
    __syncthreads();
    if (tid < 4) {
        const float* ra = (const float*)(red4 + 0);
        const float* rb = (const float*)(red4 + 1);
        out[b * 4 + tid] = ra[tid] + rb[tid] + h3_b[t * 4 + tid];
    }
}

// ---------------------------------------------------------------------------
extern "C" void kernel_launch(void* const* d_in, const int* in_sizes, int n_in,
                              void* d_out, int out_size, void* d_ws, size_t ws_size,
                              hipStream_t stream) {
    (void)in_sizes; (void)n_in; (void)out_size;
    const float* images   = (const float*)d_in[0];
    const float* prop     = (const float*)d_in[1];
    const int*   task_ids = (const int*)d_in[2];
    const float* c1_w = (const float*)d_in[3];
    const float* c1_b = (const float*)d_in[4];
    const float* c2_w = (const float*)d_in[5];
    const float* c2_b = (const float*)d_in[6];
    const float* c3_w = (const float*)d_in[7];
    const float* c3_b = (const float*)d_in[8];
    const float* p1_w = (const float*)d_in[9];
    const float* p1_b = (const float*)d_in[10];
    const float* p2_w = (const float*)d_in[11];
    const float* p2_b = (const float*)d_in[12];
    const float* f1_w = (const float*)d_in[13];
    const float* f1_b = (const float*)d_in[14];
    const float* f2_w = (const float*)d_in[15];
    const float* f2_b = (const float*)d_in[16];
    const float* temb = (const float*)d_in[17];
    const float* g_w  = (const float*)d_in[18];
    const float* g_b  = (const float*)d_in[19];
    const float* h1_w = (const float*)d_in[20];
    const float* h1_b = (const float*)d_in[21];
    const float* h2_w = (const float*)d_in[22];
    const float* h2_b = (const float*)d_in[23];
    const float* h3_w = (const float*)d_in[24];
    const float* h3_b = (const float*)d_in[25];
    float* out = (float*)d_out;

    const size_t per_img = (size_t)65 * 65 * 64 * 2 + (size_t)33 * 33 * 128 * 2;
    const size_t fixed   = (size_t)256 * 256 * 4 + 1728 * 4 +
                           (size_t)73728 * 2 + (size_t)294912 * 2 + 4096;
    int CHI = 64;
    if (ws_size >= fixed + per_img * 256) CHI = 256;
    else if (ws_size >= fixed + per_img * 128) CHI = 128;

    char* ws = (char*)d_ws;
    size_t off = 0;
    auto alloc = [&](size_t bytes) {
        void* p = ws + off;
        off += (bytes + 255) & ~(size_t)255;
        return p;
    };
    __hip_bfloat16* act1 = (__hip_bfloat16*)alloc((size_t)CHI * 65 * 65 * 64 * 2);
    __hip_bfloat16* act2 = (__hip_bfloat16*)alloc((size_t)CHI * 33 * 33 * 128 * 2);
    float*          vbuf = (float*)alloc((size_t)256 * 256 * 4);
    float*          w1t  = (float*)alloc((size_t)1728 * 4);
    __hip_bfloat16* w2t  = (__hip_bfloat16*)alloc((size_t)73728 * 2);
    __hip_bfloat16* w3t  = (__hip_bfloat16*)alloc((size_t)294912 * 2);

    halo_zero_kernel<<<dim3(CHI), 256, 0, stream>>>(
        (uint4*)act1, (uint4*)act2, (float4*)vbuf);
    transpose_w1_kernel<<<DIV_UP(1728, 256), 256, 0, stream>>>(c1_w, w1t);
    repack_w_kernel<<<DIV_UP(73728, 256), 256, 0, stream>>>(c2_w, w2t, 128, 64);
    repack_w_kernel<<<DIV_UP(294912, 256), 256, 0, stream>>>(c3_w, w3t, 256, 128);

    for (int c0 = 0; c0 < 256; c0 += CHI) {
        const float* img_c = images + (size_t)c0 * 3 * 128 * 128;
        conv1_kernel<<<dim3(64, CHI), dim3(256), 0, stream>>>(
            img_c, w1t, c1_b, act1);
        conv2_gemm_kernel<<<dim3(CHI * 8), 256, 0, stream>>>(
            act1, w2t, c2_b, act2);
        conv3_gemm_pool_kernel<<<dim3(CHI * 2, 2), 256, 0, stream>>>(
            act2, w3t, c3_b, vbuf + (size_t)c0 * 256);
    }
    tail_kernel<<<256, 256, 0, stream>>>(prop, task_ids, p1_w, p1_b, p2_w, p2_b,
                                         vbuf, f1_w, f1_b, f2_w, f2_b, temb,
                                         g_w, g_b, h1_w, h1_b, h2_w, h2_b,
                                         h3_w, h3_b, out);
}